// Round 4
// baseline (14667.981 us; speedup 1.0000x reference)
//
#include <hip/hip_runtime.h>
#include <cstdint>
#include <cstddef>
#include <cfloat>

// Persistent Seq2Seq LSTM v2 (B=32,S=T=64,E=256,H=512,V=32000), fp32.
// vs R2 (17ms): contention-free flag barrier (no single-line RMW chain),
// 512 thr/WG (2 waves/SIMD), kq=16 layouts, fc chunk streaming w/ reg
// prefetch, argmax folded into cell0 phase. Weights LDS-resident per phase,
// c-state in registers, h ping-pong in ws.

#define NWG   256
#define NTHR  512
#define BSZ   32
#define SLEN  64
#define TLEN  64
#define EDIM  256
#define HDIM  512
#define VOUT  32000
#define FCWGS 250
#define FCR   128          // fc rows per WG
#define CHR   16           // fc rows per chunk
#define NCHK  (FCR / CHR)  // 8

#define XS0 20                      // EDIM slice stride: 16 + 4 (16B-aligned, bank-spread)
#define HSL 36                      // HDIM slice stride: 32 + 4
#define RS0 (16 * XS0 + 16 * HSL)   // 896 floats per cell0 row
#define RS1 (16 * HSL + 16 * HSL)   // 1152 floats per cell1 row

struct SMem {
    float w0[8 * RS0];          // 28.7 KB
    float w1[8 * RS1];          // 36.9 KB
    float fcc[CHR * 16 * HSL];  // 36.9 KB
    float ls[FCR * 33];         // 16.9 KB
    float zsh[8 * 32];
    float cmv[4 * 32];
    int   cmi[4 * 32];
    float bsum0[8], bsum1[8];
    float fcb_s[FCR];
    int   tok[BSZ];
    int   llen[BSZ];
};                              // ~122 KB -> 1 WG/CU

// ---------------------------------------------------------- grid barrier ----
// Arrival: per-WG flag line (release store, no RMW contention).
// WG0: 256 threads poll 256 flags in parallel -> publish sense (release).
// Everyone spins on sense (read-shared). Epochs monotone; '<' compare makes
// early next-epoch arrivals count correctly.
__device__ __forceinline__ void gridbar(unsigned* flags, unsigned* sense,
                                        unsigned& epoch)
{
    __syncthreads();
    epoch++;
    if (threadIdx.x == 0) {
        __threadfence();
        __hip_atomic_store(&flags[blockIdx.x], epoch, __ATOMIC_RELEASE,
                           __HIP_MEMORY_SCOPE_AGENT);
    }
    if (blockIdx.x == 0) {
        if (threadIdx.x < NWG) {
            while (__hip_atomic_load(&flags[threadIdx.x], __ATOMIC_ACQUIRE,
                                     __HIP_MEMORY_SCOPE_AGENT) < epoch)
                __builtin_amdgcn_s_sleep(1);
        }
        __syncthreads();
        if (threadIdx.x == 0)
            __hip_atomic_store(sense, epoch, __ATOMIC_RELEASE,
                               __HIP_MEMORY_SCOPE_AGENT);
    }
    if (threadIdx.x == 0) {
        while (__hip_atomic_load(sense, __ATOMIC_ACQUIRE,
                                 __HIP_MEMORY_SCOPE_AGENT) < epoch)
            __builtin_amdgcn_s_sleep(1);
        __threadfence();
    }
    __syncthreads();
}

// ------------------------------------------------------- weight staging -----
template<int KIN>
__device__ __forceinline__ void stage_w(float* dst,
        const float* __restrict__ Wih, const float* __restrict__ Whh,
        const float* __restrict__ bih, const float* __restrict__ bhh,
        float* bsum, int j0)
{
    constexpr int XC = KIN / 16;
    constexpr int XS = (KIN == 256) ? XS0 : HSL;
    constexpr int RS = (KIN == 256) ? RS0 : RS1;
    const int tid = threadIdx.x;
    constexpr int nf4x = KIN / 4;
    for (int tt = tid; tt < 8 * nf4x; tt += NTHR) {
        int r = tt / nf4x, k = (tt % nf4x) * 4;
        int row = (r >> 1) * HDIM + j0 + (r & 1);
        float4 v = *(const float4*)(Wih + (size_t)row * KIN + k);
        *(float4*)(dst + r * RS + (k / XC) * XS + (k % XC)) = v;
    }
    for (int tt = tid; tt < 8 * 128; tt += NTHR) {
        int r = tt >> 7, k = (tt & 127) * 4;
        int row = (r >> 1) * HDIM + j0 + (r & 1);
        float4 v = *(const float4*)(Whh + (size_t)row * HDIM + k);
        *(float4*)(dst + r * RS + 16 * XS + (k >> 5) * HSL + (k & 31)) = v;
    }
    if (tid < 8) {
        int row = (tid >> 1) * HDIM + j0 + (tid & 1);
        bsum[tid] = bih[row] + bhh[row];
    }
}

// ------------------------------------------------------------- LSTM cell ----
// lane = (bl:4 x kq:16); wave covers 4 b's; 8 z-rows per WG (2 j x 4 gates).
template<int KIN>
__device__ __forceinline__ void cell_run(SMem& sm, const float* __restrict__ w,
        const float* bsum, const float* __restrict__ xrow,
        const float* __restrict__ hin, float* __restrict__ hout,
        float& creg, bool domask, int s, int j0)
{
    constexpr int XC = KIN / 16;
    constexpr int XS = (KIN == 256) ? XS0 : HSL;
    constexpr int RS = (KIN == 256) ? RS0 : RS1;
    const int tid = threadIdx.x;
    const int wave = tid >> 6, lane = tid & 63, kq = lane & 15, bl = lane >> 4;
    const int b = wave * 4 + bl;

    float4 xr[XC / 4];
#pragma unroll
    for (int i = 0; i < XC / 4; i++)
        xr[i] = *(const float4*)(xrow + kq * XC + i * 4);
    float4 hr[8];
    const float* hp = hin + (size_t)b * HDIM + kq * 32;
#pragma unroll
    for (int i = 0; i < 8; i++) hr[i] = *(const float4*)(hp + i * 4);

    __syncthreads();   // zsh free (previous consumers done)
#pragma unroll
    for (int r = 0; r < 8; r++) {
        float acc = 0.f;
        const float* wx = w + r * RS + kq * XS;
#pragma unroll
        for (int i = 0; i < XC / 4; i++) {
            float4 t4 = *(const float4*)(wx + i * 4);
            acc += t4.x * xr[i].x + t4.y * xr[i].y + t4.z * xr[i].z + t4.w * xr[i].w;
        }
        const float* wh = w + r * RS + 16 * XS + kq * HSL;
#pragma unroll
        for (int i = 0; i < 8; i++) {
            float4 t4 = *(const float4*)(wh + i * 4);
            acc += t4.x * hr[i].x + t4.y * hr[i].y + t4.z * hr[i].z + t4.w * hr[i].w;
        }
        acc += __shfl_xor(acc, 1);
        acc += __shfl_xor(acc, 2);
        acc += __shfl_xor(acc, 4);
        acc += __shfl_xor(acc, 8);
        if (kq == 0) sm.zsh[r * 32 + b] = acc + bsum[r];
    }
    __syncthreads();
    if (tid < 64) {
        int jl = tid >> 5, bb = tid & 31;
        float zi = sm.zsh[(0 + jl) * 32 + bb];
        float zf = sm.zsh[(2 + jl) * 32 + bb];
        float zg = sm.zsh[(4 + jl) * 32 + bb];
        float zo = sm.zsh[(6 + jl) * 32 + bb];
        float iv = 1.f / (1.f + expf(-zi));
        float fv = 1.f / (1.f + expf(-zf));
        float gv = tanhf(zg);
        float ov = 1.f / (1.f + expf(-zo));
        float c2 = fv * creg + iv * gv;
        float h2 = ov * tanhf(c2);
        size_t off = (size_t)bb * HDIM + j0 + jl;
        bool m = domask ? (s < sm.llen[bb]) : true;
        float hold = hin[off];
        hout[off] = m ? h2 : hold;
        creg      = m ? c2 : creg;
    }
}

// --------------------------------------------------------------------- fc ---
// wave: b-half = w&1, row-quarter-in-chunk = w>>1. lane = (bg:4 x kq:16),
// 4 b's per lane (hreg 128 VGPR). 8 chunks x 16 rows, reg prefetch 1 deep.
__device__ __forceinline__ void fc_run(SMem& sm, const float* __restrict__ h,
        const float* __restrict__ fcW, float* __restrict__ out, int t, int g,
        float* __restrict__ cand_val, int* __restrict__ cand_idx)
{
    const int tid = threadIdx.x;
    const int wave = tid >> 6, lane = tid & 63, kq = lane & 15, bg = lane >> 4;
    const int bh = wave & 1, qr = wave >> 1;
    const int bb = bh * 16 + bg * 4;
    const size_t v0 = (size_t)g * FCR;

    float4 hreg[4][8];
#pragma unroll
    for (int j = 0; j < 4; j++) {
        const float* hp = h + (size_t)(bb + j) * HDIM + kq * 32;
#pragma unroll
        for (int i = 0; i < 8; i++) hreg[j][i] = *(const float4*)(hp + i * 4);
    }

    float4 pf[4];
#pragma unroll
    for (int j = 0; j < 4; j++) {
        int tt = tid + j * NTHR;
        int r = tt >> 7, k = (tt & 127) * 4;
        pf[j] = *(const float4*)(fcW + (v0 + r) * HDIM + k);
    }

    float vmax[4]; int vidx[4];
#pragma unroll
    for (int j = 0; j < 4; j++) { vmax[j] = -FLT_MAX; vidx[j] = 0; }

    for (int c = 0; c < NCHK; c++) {
        __syncthreads();           // previous chunk fully consumed
#pragma unroll
        for (int j = 0; j < 4; j++) {
            int tt = tid + j * NTHR;
            int r = tt >> 7, k = (tt & 127) * 4;
            *(float4*)(sm.fcc + r * (16 * HSL) + (k >> 5) * HSL + (k & 31)) = pf[j];
        }
        if (c + 1 < NCHK) {
#pragma unroll
            for (int j = 0; j < 4; j++) {
                int tt = tid + j * NTHR;
                int r = tt >> 7, k = (tt & 127) * 4;
                pf[j] = *(const float4*)(fcW + (v0 + (c + 1) * CHR + r) * HDIM + k);
            }
        }
        __syncthreads();
#pragma unroll
        for (int r = 0; r < 4; r++) {
            int rc = qr * 4 + r;           // row in chunk
            int rr = c * CHR + rc;         // row in WG
            const float* wp = sm.fcc + rc * (16 * HSL) + kq * HSL;
            float a0 = 0.f, a1 = 0.f, a2 = 0.f, a3 = 0.f;
#pragma unroll
            for (int i = 0; i < 8; i++) {
                float4 w4 = *(const float4*)(wp + i * 4);
                a0 += w4.x * hreg[0][i].x + w4.y * hreg[0][i].y + w4.z * hreg[0][i].z + w4.w * hreg[0][i].w;
                a1 += w4.x * hreg[1][i].x + w4.y * hreg[1][i].y + w4.z * hreg[1][i].z + w4.w * hreg[1][i].w;
                a2 += w4.x * hreg[2][i].x + w4.y * hreg[2][i].y + w4.z * hreg[2][i].z + w4.w * hreg[2][i].w;
                a3 += w4.x * hreg[3][i].x + w4.y * hreg[3][i].y + w4.z * hreg[3][i].z + w4.w * hreg[3][i].w;
            }
#pragma unroll
            for (int m = 1; m < 16; m <<= 1) {
                a0 += __shfl_xor(a0, m);
                a1 += __shfl_xor(a1, m);
                a2 += __shfl_xor(a2, m);
                a3 += __shfl_xor(a3, m);
            }
            if (kq == 0) {
                float bias = sm.fcb_s[rr];
                float z[4] = { a0 + bias, a1 + bias, a2 + bias, a3 + bias };
#pragma unroll
                for (int j = 0; j < 4; j++) {
                    sm.ls[rr * 33 + bb + j] = z[j];
                    if (z[j] > vmax[j]) { vmax[j] = z[j]; vidx[j] = (int)(v0 + rr); }
                }
            }
        }
    }
    if (kq == 0) {
#pragma unroll
        for (int j = 0; j < 4; j++) {
            sm.cmv[qr * 32 + bb + j] = vmax[j];
            sm.cmi[qr * 32 + bb + j] = vidx[j];
        }
    }
    __syncthreads();
    if (tid < 32) {   // quarters ascending = rows ascending -> first-max kept
        float bv = sm.cmv[tid]; int bi = sm.cmi[tid];
#pragma unroll
        for (int q = 1; q < 4; q++) {
            float v = sm.cmv[q * 32 + tid]; int ix = sm.cmi[q * 32 + tid];
            if (v > bv || (v == bv && ix < bi)) { bv = v; bi = ix; }
        }
        cand_val[(size_t)tid * NWG + g] = bv;
        cand_idx[(size_t)tid * NWG + g] = bi;
    }
    // logits: lane order (b2:32 x q16:16) -> 16 lanes write consecutive 512B
    {
        int b2 = tid >> 4, q16 = tid & 15;
        float* op = out + ((size_t)b2 * TLEN + t) * VOUT + v0 + q16 * 8;
        float4 u0, u1;
        u0.x = sm.ls[(q16 * 8 + 0) * 33 + b2];
        u0.y = sm.ls[(q16 * 8 + 1) * 33 + b2];
        u0.z = sm.ls[(q16 * 8 + 2) * 33 + b2];
        u0.w = sm.ls[(q16 * 8 + 3) * 33 + b2];
        u1.x = sm.ls[(q16 * 8 + 4) * 33 + b2];
        u1.y = sm.ls[(q16 * 8 + 5) * 33 + b2];
        u1.z = sm.ls[(q16 * 8 + 6) * 33 + b2];
        u1.w = sm.ls[(q16 * 8 + 7) * 33 + b2];
        *(float4*)op = u0;
        *(float4*)(op + 4) = u1;
    }
}

// --------------------------------------------------------- main persistent --
__global__ __launch_bounds__(NTHR, 2)
void seq2seq_persist(
    const int* __restrict__ inputs, const int* __restrict__ lens,
    const float* __restrict__ enc_emb, const float* __restrict__ dec_emb,
    const float* __restrict__ eW0ih, const float* __restrict__ eW0hh,
    const float* __restrict__ eB0ih, const float* __restrict__ eB0hh,
    const float* __restrict__ eW1ih, const float* __restrict__ eW1hh,
    const float* __restrict__ eB1ih, const float* __restrict__ eB1hh,
    const float* __restrict__ dW0ih, const float* __restrict__ dW0hh,
    const float* __restrict__ dB0ih, const float* __restrict__ dB0hh,
    const float* __restrict__ dW1ih, const float* __restrict__ dW1hh,
    const float* __restrict__ dB1ih, const float* __restrict__ dB1hh,
    const float* __restrict__ fcW, const float* __restrict__ fcb,
    float* __restrict__ out,
    float* h0a, float* h0b, float* h1a, float* h1b,
    float* cand_val, int* cand_idx, unsigned* flags, unsigned* sense)
{
    __shared__ SMem sm;
    const int g = blockIdx.x;
    const int tid = threadIdx.x;
    const int j0 = g * 2;
    unsigned epoch = 0;

    const int wave = tid >> 6, lane = tid & 63, bl = lane >> 4;
    const int b = wave * 4 + bl;

    float* h0[2] = { h0a, h0b };
    float* h1[2] = { h1a, h1b };

    // zero initial h state (each WG zeroes its 64-float slice of h0a/h1a)
    if (tid < 64) {
        h0a[g * 64 + tid] = 0.f;
        h1a[g * 64 + tid] = 0.f;
    }
    stage_w<EDIM>(sm.w0, eW0ih, eW0hh, eB0ih, eB0hh, sm.bsum0, j0);
    stage_w<HDIM>(sm.w1, eW1ih, eW1hh, eB1ih, eB1hh, sm.bsum1, j0);
    if (tid < BSZ) sm.llen[tid] = lens[tid];
    float c0r = 0.f, c1r = 0.f;
    gridbar(flags, sense, epoch);

    // ---- encoder: pipelined, 1 barrier/phase ----
    for (int s = 0; s <= SLEN; ++s) {
        int p = s & 1;
        if (s < SLEN) {
            const float* x0 = enc_emb + (size_t)inputs[b * SLEN + s] * EDIM;
            cell_run<EDIM>(sm, sm.w0, sm.bsum0, x0, h0[p], h0[p ^ 1], c0r,
                           true, s, j0);
        }
        if (s >= 1) {
            int q = (s - 1) & 1;
            cell_run<HDIM>(sm, sm.w1, sm.bsum1, h0[p] + (size_t)b * HDIM,
                           h1[q], h1[q ^ 1], c1r, true, s - 1, j0);
        }
        gridbar(flags, sense, epoch);
    }
    // finals in h0[0], h1[0]

    // ---- decoder setup ----
    stage_w<EDIM>(sm.w0, dW0ih, dW0hh, dB0ih, dB0hh, sm.bsum0, j0);
    stage_w<HDIM>(sm.w1, dW1ih, dW1hh, dB1ih, dB1hh, sm.bsum1, j0);
    if (g < FCWGS)
        for (int i = tid; i < FCR; i += NTHR) sm.fcb_s[i] = fcb[g * FCR + i];
    c0r = 0.f; c1r = 0.f;
    __syncthreads();

    // ---- decoder: 3 barriers/step ----
    for (int t = 0; t < TLEN; ++t) {
        int p = t & 1;
        if (t == 0) {
            if (tid < BSZ) sm.tok[tid] = 1;
        } else if (tid < 256) {
            int bq = tid >> 3, q = tid & 7;
            float bv = -FLT_MAX; int bi = 0x7fffffff;
            for (int gg = q; gg < FCWGS; gg += 8) {
                float v = cand_val[(size_t)bq * NWG + gg];
                int  ix = cand_idx[(size_t)bq * NWG + gg];
                if (v > bv || (v == bv && ix < bi)) { bv = v; bi = ix; }
            }
#pragma unroll
            for (int m = 1; m < 8; m <<= 1) {
                float ov = __shfl_xor(bv, m); int oi = __shfl_xor(bi, m);
                if (ov > bv || (ov == bv && oi < bi)) { bv = ov; bi = oi; }
            }
            if (q == 0) sm.tok[bq] = bi;
        }
        __syncthreads();
        const float* x0 = dec_emb + (size_t)sm.tok[b] * EDIM;
        cell_run<EDIM>(sm, sm.w0, sm.bsum0, x0, h0[p], h0[p ^ 1], c0r,
                       false, 0, j0);
        gridbar(flags, sense, epoch);
        cell_run<HDIM>(sm, sm.w1, sm.bsum1, h0[p ^ 1] + (size_t)b * HDIM,
                       h1[p], h1[p ^ 1], c1r, false, 0, j0);
        gridbar(flags, sense, epoch);
        if (g < FCWGS)
            fc_run(sm, h1[p ^ 1], fcW, out, t, g, cand_val, cand_idx);
        gridbar(flags, sense, epoch);
    }
}

// ------------------------------------------------------------------- init ---
__global__ void initk(unsigned* flags)
{
    int i = blockIdx.x * 256 + threadIdx.x;
    if (i < NWG + 1) flags[i] = 0u;   // flags[256] + sense
}

// ----------------------------------------------------------------- driver ---
extern "C" void kernel_launch(void* const* d_in, const int* in_sizes, int n_in,
                              void* d_out, int out_size, void* d_ws, size_t ws_size,
                              hipStream_t stream)
{
    const int*   inputs  = (const int*)d_in[0];
    const int*   lens    = (const int*)d_in[3];
    const float* enc_emb = (const float*)d_in[4];
    const float* dec_emb = (const float*)d_in[5];
    const float* W[16];
    for (int i = 0; i < 16; i++) W[i] = (const float*)d_in[6 + i];
    const float* fcW = (const float*)d_in[22];
    const float* fcb = (const float*)d_in[23];
    float* out = (float*)d_out;

    float* ws = (float*)d_ws;
    float* h0a = ws;
    float* h0b = ws + 16384;
    float* h1a = ws + 32768;
    float* h1b = ws + 49152;
    float* cand_val = ws + 65536;                   // 32*256
    int*   cand_idx = (int*)(ws + 65536 + 8192);    // 32*256
    unsigned* flags = (unsigned*)(ws + 65536 + 16384);  // 256 + 1

    initk<<<2, 256, 0, stream>>>(flags);
    seq2seq_persist<<<NWG, NTHR, 0, stream>>>(
        inputs, lens, enc_emb, dec_emb,
        W[0], W[1], W[2], W[3], W[4], W[5], W[6], W[7],
        W[8], W[9], W[10], W[11], W[12], W[13], W[14], W[15],
        fcW, fcb, out,
        h0a, h0b, h1a, h1b, cand_val, cand_idx, flags, flags + NWG);
}

// Round 5
// 10804.584 us; speedup vs baseline: 1.3576x; 1.3576x over previous
//
#include <hip/hip_runtime.h>
#include <cstdint>
#include <cstddef>
#include <cfloat>

// Persistent Seq2Seq LSTM v3 (B=32,S=T=64,E=256,H=512,V=32000), fp32.
// R5 experiment: FENCE-FREE grid barrier. All cross-WG state (h, cand, flags)
// goes through relaxed AGENT-scope atomics (coherent at LLC, no L2 wb/inv);
// ordering by s_waitcnt vmcnt(0) before flag store. Read-only data plain.
// Logits plain (write-only; no fence ever executes -> dirty L2 harmless).
// Weights LDS-resident per phase; c-state in registers; h ping-pong in ws.

#define NWG   256
#define NTHR  512
#define BSZ   32
#define SLEN  64
#define TLEN  64
#define EDIM  256
#define HDIM  512
#define VOUT  32000
#define FCWGS 250
#define FCR   128          // fc rows per WG
#define CHR   16           // fc rows per chunk
#define NCHK  (FCR / CHR)  // 8
#define FSTR  16           // flag stride (u32) -> one cacheline per flag

#define XS0 20                      // EDIM slice stride: 16+4
#define HSL 36                      // HDIM slice stride: 32+4
#define RS0 (16 * XS0 + 16 * HSL)   // 896 floats / cell0 row
#define RS1 (16 * HSL + 16 * HSL)   // 1152 floats / cell1 row

struct SMem {
    float w0[8 * RS0];
    float w1[8 * RS1];
    float fcc[CHR * 16 * HSL];
    float ls[FCR * 33];
    float zsh[8 * 32];
    float cmv[4 * 32];
    int   cmi[4 * 32];
    float bsum0[8], bsum1[8];
    float fcb_s[FCR];
    int   tok[BSZ];
    int   llen[BSZ];
};

// ------------------------------------------------- relaxed agent atomics ----
__device__ __forceinline__ float aload(const float* p) {
    return __hip_atomic_load(p, __ATOMIC_RELAXED, __HIP_MEMORY_SCOPE_AGENT);
}
__device__ __forceinline__ void astore(float* p, float v) {
    __hip_atomic_store(p, v, __ATOMIC_RELAXED, __HIP_MEMORY_SCOPE_AGENT);
}
__device__ __forceinline__ int aloadi(const int* p) {
    return __hip_atomic_load(p, __ATOMIC_RELAXED, __HIP_MEMORY_SCOPE_AGENT);
}
__device__ __forceinline__ void astorei(int* p, int v) {
    __hip_atomic_store(p, v, __ATOMIC_RELAXED, __HIP_MEMORY_SCOPE_AGENT);
}
__device__ __forceinline__ float2 aload2(const float* p) {
    unsigned long long u = __hip_atomic_load((const unsigned long long*)p,
                              __ATOMIC_RELAXED, __HIP_MEMORY_SCOPE_AGENT);
    union { unsigned long long u; float2 f; } c; c.u = u; return c.f;
}

// ---------------------------------------------------------- grid barrier ----
// Fence-free: drain own stores (vmcnt ack = visible at coherence point),
// publish per-WG flag (relaxed atomic), every WG polls all flags directly.
__device__ __forceinline__ void gridbar(unsigned* flags, unsigned& epoch)
{
    asm volatile("s_waitcnt vmcnt(0)" ::: "memory");
    __syncthreads();
    epoch++;
    if (threadIdx.x == 0)
        __hip_atomic_store(&flags[(size_t)blockIdx.x * FSTR], epoch,
                           __ATOMIC_RELAXED, __HIP_MEMORY_SCOPE_AGENT);
    if (threadIdx.x < NWG) {
        while (__hip_atomic_load(&flags[(size_t)threadIdx.x * FSTR],
                                 __ATOMIC_RELAXED, __HIP_MEMORY_SCOPE_AGENT) < epoch)
            __builtin_amdgcn_s_sleep(8);
    }
    __syncthreads();
}

// ------------------------------------------------------- weight staging -----
template<int KIN>
__device__ __forceinline__ void stage_w(float* dst,
        const float* __restrict__ Wih, const float* __restrict__ Whh,
        const float* __restrict__ bih, const float* __restrict__ bhh,
        float* bsum, int j0)
{
    constexpr int XC = KIN / 16;
    constexpr int XS = (KIN == 256) ? XS0 : HSL;
    constexpr int RS = (KIN == 256) ? RS0 : RS1;
    const int tid = threadIdx.x;
    constexpr int nf4x = KIN / 4;
    for (int tt = tid; tt < 8 * nf4x; tt += NTHR) {
        int r = tt / nf4x, k = (tt % nf4x) * 4;
        int row = (r >> 1) * HDIM + j0 + (r & 1);
        float4 v = *(const float4*)(Wih + (size_t)row * KIN + k);
        *(float4*)(dst + r * RS + (k / XC) * XS + (k % XC)) = v;
    }
    for (int tt = tid; tt < 8 * 128; tt += NTHR) {
        int r = tt >> 7, k = (tt & 127) * 4;
        int row = (r >> 1) * HDIM + j0 + (r & 1);
        float4 v = *(const float4*)(Whh + (size_t)row * HDIM + k);
        *(float4*)(dst + r * RS + 16 * XS + (k >> 5) * HSL + (k & 31)) = v;
    }
    if (tid < 8) {
        int row = (tid >> 1) * HDIM + j0 + (tid & 1);
        bsum[tid] = bih[row] + bhh[row];
    }
}

// ------------------------------------------------------------- LSTM cell ----
// lane = (bl:4 x kq:16); 8 z-rows per WG (2 j x 4 gates).
// AX: x is cross-WG state (h0) -> atomic loads; else plain (emb rows).
template<int KIN, bool AX>
__device__ __forceinline__ void cell_run(SMem& sm, const float* __restrict__ w,
        const float* bsum, const float* __restrict__ xrow,
        const float* __restrict__ hin, float* __restrict__ hout,
        float& creg, bool domask, int s, int j0)
{
    constexpr int XC = KIN / 16;
    constexpr int XS = (KIN == 256) ? XS0 : HSL;
    constexpr int RS = (KIN == 256) ? RS0 : RS1;
    const int tid = threadIdx.x;
    const int wave = tid >> 6, lane = tid & 63, kq = lane & 15, bl = lane >> 4;
    const int b = wave * 4 + bl;

    float xv[XC];
    if (AX) {
#pragma unroll
        for (int i = 0; i < XC / 2; i++) {
            float2 t = aload2(xrow + kq * XC + i * 2);
            xv[i * 2] = t.x; xv[i * 2 + 1] = t.y;
        }
    } else {
#pragma unroll
        for (int i = 0; i < XC / 4; i++) {
            float4 t = *(const float4*)(xrow + kq * XC + i * 4);
            xv[i * 4] = t.x; xv[i * 4 + 1] = t.y; xv[i * 4 + 2] = t.z; xv[i * 4 + 3] = t.w;
        }
    }
    float hv[32];
    {
        const float* hp = hin + (size_t)b * HDIM + kq * 32;
#pragma unroll
        for (int i = 0; i < 16; i++) {
            float2 t = aload2(hp + i * 2);
            hv[i * 2] = t.x; hv[i * 2 + 1] = t.y;
        }
    }

    __syncthreads();   // zsh free (previous consumers done)
#pragma unroll
    for (int r = 0; r < 8; r++) {
        float acc = 0.f;
        const float* wx = w + r * RS + kq * XS;
#pragma unroll
        for (int i = 0; i < XC / 4; i++) {
            float4 t4 = *(const float4*)(wx + i * 4);
            acc += t4.x * xv[i*4] + t4.y * xv[i*4+1] + t4.z * xv[i*4+2] + t4.w * xv[i*4+3];
        }
        const float* wh = w + r * RS + 16 * XS + kq * HSL;
#pragma unroll
        for (int i = 0; i < 8; i++) {
            float4 t4 = *(const float4*)(wh + i * 4);
            acc += t4.x * hv[i*4] + t4.y * hv[i*4+1] + t4.z * hv[i*4+2] + t4.w * hv[i*4+3];
        }
        acc += __shfl_xor(acc, 1);
        acc += __shfl_xor(acc, 2);
        acc += __shfl_xor(acc, 4);
        acc += __shfl_xor(acc, 8);
        if (kq == 0) sm.zsh[r * 32 + b] = acc + bsum[r];
    }
    __syncthreads();
    if (tid < 64) {
        int jl = tid >> 5, bb = tid & 31;
        float zi = sm.zsh[(0 + jl) * 32 + bb];
        float zf = sm.zsh[(2 + jl) * 32 + bb];
        float zg = sm.zsh[(4 + jl) * 32 + bb];
        float zo = sm.zsh[(6 + jl) * 32 + bb];
        float iv = 1.f / (1.f + expf(-zi));
        float fv = 1.f / (1.f + expf(-zf));
        float gv = tanhf(zg);
        float ov = 1.f / (1.f + expf(-zo));
        float cold = creg;
        float c2 = fv * cold + iv * gv;
        float h2 = ov * tanhf(c2);
        size_t off = (size_t)bb * HDIM + j0 + jl;
        if (domask) {
            bool m = s < sm.llen[bb];
            if (!m) { h2 = aload(hin + off); c2 = cold; }
        }
        astore(hout + off, h2);
        creg = c2;
    }
}

// --------------------------------------------------------------------- fc ---
__device__ __forceinline__ void fc_run(SMem& sm, const float* __restrict__ h,
        const float* __restrict__ fcW, float* __restrict__ out, int t, int g,
        float* __restrict__ cand_val, int* __restrict__ cand_idx)
{
    const int tid = threadIdx.x;
    const int wave = tid >> 6, lane = tid & 63, kq = lane & 15, bg = lane >> 4;
    const int bh = wave & 1, qr = wave >> 1;
    const int bb = bh * 16 + bg * 4;
    const size_t v0 = (size_t)g * FCR;

    float hrs[4][32];
#pragma unroll
    for (int j = 0; j < 4; j++) {
        const float* hp = h + (size_t)(bb + j) * HDIM + kq * 32;
#pragma unroll
        for (int i = 0; i < 16; i++) {
            float2 u = aload2(hp + i * 2);
            hrs[j][i * 2] = u.x; hrs[j][i * 2 + 1] = u.y;
        }
    }

    float4 pf[4];
#pragma unroll
    for (int j = 0; j < 4; j++) {
        int tt = tid + j * NTHR;
        int r = tt >> 7, k = (tt & 127) * 4;
        pf[j] = *(const float4*)(fcW + (v0 + r) * HDIM + k);
    }

    float vmax[4]; int vidx[4];
#pragma unroll
    for (int j = 0; j < 4; j++) { vmax[j] = -FLT_MAX; vidx[j] = 0; }

    for (int c = 0; c < NCHK; c++) {
        __syncthreads();
#pragma unroll
        for (int j = 0; j < 4; j++) {
            int tt = tid + j * NTHR;
            int r = tt >> 7, k = (tt & 127) * 4;
            *(float4*)(sm.fcc + r * (16 * HSL) + (k >> 5) * HSL + (k & 31)) = pf[j];
        }
        if (c + 1 < NCHK) {
#pragma unroll
            for (int j = 0; j < 4; j++) {
                int tt = tid + j * NTHR;
                int r = tt >> 7, k = (tt & 127) * 4;
                pf[j] = *(const float4*)(fcW + (v0 + (c + 1) * CHR + r) * HDIM + k);
            }
        }
        __syncthreads();
#pragma unroll
        for (int r = 0; r < 4; r++) {
            int rc = qr * 4 + r;
            int rr = c * CHR + rc;
            const float* wp = sm.fcc + rc * (16 * HSL) + kq * HSL;
            float a0 = 0.f, a1 = 0.f, a2 = 0.f, a3 = 0.f;
#pragma unroll
            for (int i = 0; i < 8; i++) {
                float4 w4 = *(const float4*)(wp + i * 4);
                a0 += w4.x * hrs[0][i*4] + w4.y * hrs[0][i*4+1] + w4.z * hrs[0][i*4+2] + w4.w * hrs[0][i*4+3];
                a1 += w4.x * hrs[1][i*4] + w4.y * hrs[1][i*4+1] + w4.z * hrs[1][i*4+2] + w4.w * hrs[1][i*4+3];
                a2 += w4.x * hrs[2][i*4] + w4.y * hrs[2][i*4+1] + w4.z * hrs[2][i*4+2] + w4.w * hrs[2][i*4+3];
                a3 += w4.x * hrs[3][i*4] + w4.y * hrs[3][i*4+1] + w4.z * hrs[3][i*4+2] + w4.w * hrs[3][i*4+3];
            }
#pragma unroll
            for (int m = 1; m < 16; m <<= 1) {
                a0 += __shfl_xor(a0, m);
                a1 += __shfl_xor(a1, m);
                a2 += __shfl_xor(a2, m);
                a3 += __shfl_xor(a3, m);
            }
            if (kq == 0) {
                float bias = sm.fcb_s[rr];
                float z[4] = { a0 + bias, a1 + bias, a2 + bias, a3 + bias };
#pragma unroll
                for (int j = 0; j < 4; j++) {
                    sm.ls[rr * 33 + bb + j] = z[j];
                    if (z[j] > vmax[j]) { vmax[j] = z[j]; vidx[j] = (int)(v0 + rr); }
                }
            }
        }
    }
    if (kq == 0) {
#pragma unroll
        for (int j = 0; j < 4; j++) {
            sm.cmv[qr * 32 + bb + j] = vmax[j];
            sm.cmi[qr * 32 + bb + j] = vidx[j];
        }
    }
    __syncthreads();
    if (tid < 32) {
        float bv = sm.cmv[tid]; int bi = sm.cmi[tid];
#pragma unroll
        for (int q = 1; q < 4; q++) {
            float v = sm.cmv[q * 32 + tid]; int ix = sm.cmi[q * 32 + tid];
            if (v > bv || (v == bv && ix < bi)) { bv = v; bi = ix; }
        }
        astore(&cand_val[(size_t)tid * NWG + g], bv);
        astorei(&cand_idx[(size_t)tid * NWG + g], bi);
    }
    // logits: plain stores (write-only; no fences anywhere -> dirty L2 free)
    {
        int b2 = tid >> 4, q16 = tid & 15;
        float* op = out + ((size_t)b2 * TLEN + t) * VOUT + v0 + q16 * 8;
        float4 u0, u1;
        u0.x = sm.ls[(q16 * 8 + 0) * 33 + b2];
        u0.y = sm.ls[(q16 * 8 + 1) * 33 + b2];
        u0.z = sm.ls[(q16 * 8 + 2) * 33 + b2];
        u0.w = sm.ls[(q16 * 8 + 3) * 33 + b2];
        u1.x = sm.ls[(q16 * 8 + 4) * 33 + b2];
        u1.y = sm.ls[(q16 * 8 + 5) * 33 + b2];
        u1.z = sm.ls[(q16 * 8 + 6) * 33 + b2];
        u1.w = sm.ls[(q16 * 8 + 7) * 33 + b2];
        *(float4*)op = u0;
        *(float4*)(op + 4) = u1;
    }
}

// --------------------------------------------------------- main persistent --
__global__ __launch_bounds__(NTHR, 2)
void seq2seq_persist(
    const int* __restrict__ inputs, const int* __restrict__ lens,
    const float* __restrict__ enc_emb, const float* __restrict__ dec_emb,
    const float* __restrict__ eW0ih, const float* __restrict__ eW0hh,
    const float* __restrict__ eB0ih, const float* __restrict__ eB0hh,
    const float* __restrict__ eW1ih, const float* __restrict__ eW1hh,
    const float* __restrict__ eB1ih, const float* __restrict__ eB1hh,
    const float* __restrict__ dW0ih, const float* __restrict__ dW0hh,
    const float* __restrict__ dB0ih, const float* __restrict__ dB0hh,
    const float* __restrict__ dW1ih, const float* __restrict__ dW1hh,
    const float* __restrict__ dB1ih, const float* __restrict__ dB1hh,
    const float* __restrict__ fcW, const float* __restrict__ fcb,
    float* __restrict__ out,
    float* h0a, float* h0b, float* h1a, float* h1b,
    float* cand_val, int* cand_idx, unsigned* flags)
{
    __shared__ SMem sm;
    const int g = blockIdx.x;
    const int tid = threadIdx.x;
    const int j0 = g * 2;
    unsigned epoch = 0;

    const int wave = tid >> 6, lane = tid & 63, bl = lane >> 4;
    const int b = wave * 4 + bl;

    float* h0[2] = { h0a, h0b };
    float* h1[2] = { h1a, h1b };

    // zero initial h state (atomic stores: readers use atomic loads)
    if (tid < 64) {
        astore(&h0a[g * 64 + tid], 0.f);
        astore(&h1a[g * 64 + tid], 0.f);
    }
    stage_w<EDIM>(sm.w0, eW0ih, eW0hh, eB0ih, eB0hh, sm.bsum0, j0);
    stage_w<HDIM>(sm.w1, eW1ih, eW1hh, eB1ih, eB1hh, sm.bsum1, j0);
    if (tid < BSZ) sm.llen[tid] = lens[tid];
    float c0r = 0.f, c1r = 0.f;
    gridbar(flags, epoch);

    // ---- encoder: pipelined, 1 barrier/phase ----
    for (int s = 0; s <= SLEN; ++s) {
        int p = s & 1;
        if (s < SLEN) {
            const float* x0 = enc_emb + (size_t)inputs[b * SLEN + s] * EDIM;
            cell_run<EDIM, false>(sm, sm.w0, sm.bsum0, x0, h0[p], h0[p ^ 1], c0r,
                                  true, s, j0);
        }
        if (s >= 1) {
            int q = (s - 1) & 1;
            cell_run<HDIM, true>(sm, sm.w1, sm.bsum1, h0[p] + (size_t)b * HDIM,
                                 h1[q], h1[q ^ 1], c1r, true, s - 1, j0);
        }
        gridbar(flags, epoch);
    }
    // finals in h0[0], h1[0]

    // ---- decoder setup ----
    stage_w<EDIM>(sm.w0, dW0ih, dW0hh, dB0ih, dB0hh, sm.bsum0, j0);
    stage_w<HDIM>(sm.w1, dW1ih, dW1hh, dB1ih, dB1hh, sm.bsum1, j0);
    if (g < FCWGS)
        for (int i = tid; i < FCR; i += NTHR) sm.fcb_s[i] = fcb[g * FCR + i];
    c0r = 0.f; c1r = 0.f;
    __syncthreads();

    // ---- decoder: 3 barriers/step ----
    for (int t = 0; t < TLEN; ++t) {
        int p = t & 1;
        if (t == 0) {
            if (tid < BSZ) sm.tok[tid] = 1;
        } else if (tid < 256) {
            int bq = tid >> 3, q = tid & 7;
            float bv = -FLT_MAX; int bi = 0x7fffffff;
            for (int gg = q; gg < FCWGS; gg += 8) {
                float v = aload(&cand_val[(size_t)bq * NWG + gg]);
                int  ix = aloadi(&cand_idx[(size_t)bq * NWG + gg]);
                if (v > bv || (v == bv && ix < bi)) { bv = v; bi = ix; }
            }
#pragma unroll
            for (int m = 1; m < 8; m <<= 1) {
                float ov = __shfl_xor(bv, m); int oi = __shfl_xor(bi, m);
                if (ov > bv || (ov == bv && oi < bi)) { bv = ov; bi = oi; }
            }
            if (q == 0) sm.tok[bq] = bi;
        }
        __syncthreads();
        const float* x0 = dec_emb + (size_t)sm.tok[b] * EDIM;
        cell_run<EDIM, false>(sm, sm.w0, sm.bsum0, x0, h0[p], h0[p ^ 1], c0r,
                              false, 0, j0);
        gridbar(flags, epoch);
        cell_run<HDIM, true>(sm, sm.w1, sm.bsum1, h0[p ^ 1] + (size_t)b * HDIM,
                             h1[p], h1[p ^ 1], c1r, false, 0, j0);
        gridbar(flags, epoch);
        if (g < FCWGS)
            fc_run(sm, h1[p ^ 1], fcW, out, t, g, cand_val, cand_idx);
        gridbar(flags, epoch);
    }
}

// ------------------------------------------------------------------- init ---
__global__ void initk(unsigned* flags)
{
    int i = blockIdx.x * 256 + threadIdx.x;
    if (i < NWG * FSTR) flags[i] = 0u;
}

// ----------------------------------------------------------------- driver ---
extern "C" void kernel_launch(void* const* d_in, const int* in_sizes, int n_in,
                              void* d_out, int out_size, void* d_ws, size_t ws_size,
                              hipStream_t stream)
{
    const int*   inputs  = (const int*)d_in[0];
    const int*   lens    = (const int*)d_in[3];
    const float* enc_emb = (const float*)d_in[4];
    const float* dec_emb = (const float*)d_in[5];
    const float* W[16];
    for (int i = 0; i < 16; i++) W[i] = (const float*)d_in[6 + i];
    const float* fcW = (const float*)d_in[22];
    const float* fcb = (const float*)d_in[23];
    float* out = (float*)d_out;

    float* ws = (float*)d_ws;
    float* h0a = ws;
    float* h0b = ws + 16384;
    float* h1a = ws + 32768;
    float* h1b = ws + 49152;
    float* cand_val = ws + 65536;                       // 32*256
    int*   cand_idx = (int*)(ws + 65536 + 8192);        // 32*256
    unsigned* flags = (unsigned*)(ws + 65536 + 16384);  // 256*16

    initk<<<16, 256, 0, stream>>>(flags);
    seq2seq_persist<<<NWG, NTHR, 0, stream>>>(
        inputs, lens, enc_emb, dec_emb,
        W[0], W[1], W[2], W[3], W[4], W[5], W[6], W[7],
        W[8], W[9], W[10], W[11], W[12], W[13], W[14], W[15],
        fcW, fcb, out,
        h0a, h0b, h1a, h1b, cand_val, cand_idx, flags);
}